// Round 7
// baseline (505.208 us; speedup 1.0000x reference)
//
#include <hip/hip_runtime.h>
#include <hip/hip_bf16.h>

typedef __bf16 bf16x8 __attribute__((ext_vector_type(8)));
typedef float f32x4 __attribute__((ext_vector_type(4)));
typedef unsigned short u16;
typedef unsigned short us4 __attribute__((ext_vector_type(4)));
typedef unsigned int u32;

// ---------- bf16 helpers (RNE) ----------
__device__ __forceinline__ u16 f2bf(float x) {
  union { float f; u32 u; } v; v.f = x;
  u32 r = v.u + 0x7FFFu + ((v.u >> 16) & 1u);
  return (u16)(r >> 16);
}
__device__ __forceinline__ float bf2f(u16 h) {
  union { u32 u; float f; } v; v.u = ((u32)h) << 16;
  return v.f;
}

__device__ __forceinline__ void glds16(const void* g, void* l) {
  __builtin_amdgcn_global_load_lds(
      (const __attribute__((address_space(1))) void*)g,
      (__attribute__((address_space(3))) void*)l, 16, 0, 0);
}

// ---------- 256x256 template GEMM: C[M,N] = A[M,K] * B[N,K]^T ----------
// BM=BN=256, BK=32. 8 waves = 2M x 4N; per-wave 128x64 (acc 8x4 = 128 VGPR).
// LDS: 4 buffers x (A 16KB + B 16KB) = 128KB, row-pair packed [128][64]:
// (orig row r, col c) -> lds u16 idx (r>>1)*64 + (r&1)*32 + c  => b128 frag
// reads cover 1024 consecutive bytes per wave = conflict-free streaming.
// Pipeline: stage tile t+2 during tile t (2 glds A in phase0, 2 glds B in
// phase1), counted s_waitcnt vmcnt(4) at tile end (never 0 in steady state).
// Phase: {ds_reads + glds -> s_barrier -> lgkmcnt(0) -> setprio(1) ->
// 16 MFMA -> setprio(0)}; 2 phases per K-tile.
// K-split: kz splits the virtual-K tile range; EPI0 accumulates fp32 partials
// via unsafeAtomicAdd into a zero-initialized buffer (2 commutative adds ->
// deterministic).
// NSEG==3: A,B packed [hi|lo] (ld=2*K0, K0==1024): Ah*Bh + Al*Bh + Ah*Bl.
// EPI: 0 = fp32 atomic-accumulate; 2 = bf16 store.
template<int NSEG, int EPI>
__global__ __launch_bounds__(512, 1)
void gemm256(const u16* __restrict__ A, const u16* __restrict__ B,
             void* __restrict__ Cout, int K0, int lda, int ldb, int ldc,
             long sA, long sB, long sC,
             int nb, int nx, int ny, int tpz)
{
  __shared__ __align__(1024) u16 lds[4][2][8192];   // [buf][A/B][packed]

  // bijective XCD-chunk swizzle (nwg % 8 == 0)
  const int d = blockIdx.x;
  const int Lx = (d & 7) * ((int)gridDim.x >> 3) + (d >> 3);
  int tmp = Lx;
  const int by = tmp % ny; tmp /= ny;
  const int bx = tmp % nx; tmp /= nx;
  const int bz = tmp % nb; tmp /= nb;
  const int kz = tmp;

  const int brow = bx * 256;
  const int bcol = by * 256;

  const int tid  = threadIdx.x;
  const int wid  = tid >> 6;        // 0..7
  const int lane = tid & 63;
  const int wrm  = wid >> 2;        // 0..1  (128-row half)
  const int wcn  = wid & 3;         // 0..3  (64-col quarter)

  const u16* Ab = A + (long)bz * sA + (long)brow * lda;
  const u16* Bb = B + (long)bz * sB + (long)bcol * ldb;

  f32x4 acc[8][4];
#pragma unroll
  for (int m = 0; m < 8; ++m)
#pragma unroll
    for (int n = 0; n < 4; ++n) acc[m][n] = (f32x4){0.f, 0.f, 0.f, 0.f};

  // fragment read offset (u16): row r=R0+(lane&15), col (lane>>4)*8
  const int r15 = lane & 15;
  const int laneRd = ((r15 >> 1) * 64) + ((r15 & 1) * 32) + ((lane >> 4) * 8);

  // staging per-lane source pattern: 16 rows x 32 cols per glds; matches
  // the row-pair packed dest (lane l writes LDS bytes l*16..+16)
  const int srow = ((lane >> 3) * 2) + ((lane & 7) >> 2);  // 0..15
  const int scol = (lane & 3) * 8;                          // elem offset

  // global A/B base for virtual tile t (kte = K elem offset)
  auto srcAB = [&](int t, const u16*& Aseg, const u16*& Bseg) {
    int seg, kte;
    if (NSEG == 3) { seg = t >> 5; kte = (t & 31) << 5; }  // K0==1024
    else           { seg = 0;      kte = t << 5; }
    Aseg = Ab + ((NSEG == 3 && seg == 1) ? K0 : 0) + kte;
    Bseg = Bb + ((NSEG == 3 && seg == 2) ? K0 : 0) + kte;
  };
  // stage one operand (16KB): 2 glds per wave; wave wid covers rows wid*32..+31
  auto stage2 = [&](const u16* base, int ld, u16* dstOp) {
#pragma unroll
    for (int q = 0; q < 2; ++q) {
      const int rowbase = wid * 32 + q * 16;
      glds16(base + (long)(rowbase + srow) * ld + scol,
             dstOp + (rowbase >> 1) * 64);
    }
  };

  const int t0 = kz * tpz;

  // prologue: stage tiles t0 -> buf0, t0+1 -> buf1; wait tile t0 (4 of 8)
  {
    const u16 *As, *Bs;
    srcAB(t0, As, Bs);
    stage2(As, lda, lds[0][0]);
    stage2(Bs, ldb, lds[0][1]);
    srcAB(t0 + 1, As, Bs);
    stage2(As, lda, lds[1][0]);
    stage2(Bs, ldb, lds[1][1]);
  }
  asm volatile("s_waitcnt vmcnt(4)" ::: "memory");
  __builtin_amdgcn_s_barrier();

  for (int tau = 0; tau < tpz; ++tau) {
    const u16* LA = lds[tau & 3][0];
    const u16* LB = lds[tau & 3][1];
    const bool pre = (tau + 2 < tpz);
    const u16 *Asg = nullptr, *Bsg = nullptr;
    u16 *LAs = nullptr, *LBs = nullptr;
    if (pre) {
      srcAB(t0 + tau + 2, Asg, Bsg);
      LAs = lds[(tau + 2) & 3][0];
      LBs = lds[(tau + 2) & 3][1];
    }

    bf16x8 bv[4];
#pragma unroll
    for (int p = 0; p < 2; ++p) {
      bf16x8 av[4];
#pragma unroll
      for (int j = 0; j < 4; ++j)
        av[j] = *(const bf16x8*)(LA + (wrm * 128 + (p * 4 + j) * 16) * 32 + laneRd);
      if (p == 0) {
#pragma unroll
        for (int n = 0; n < 4; ++n)
          bv[n] = *(const bf16x8*)(LB + (wcn * 64 + n * 16) * 32 + laneRd);
        if (pre) stage2(Asg, lda, LAs);
      } else {
        if (pre) stage2(Bsg, ldb, LBs);
      }
      __builtin_amdgcn_s_barrier();
      asm volatile("s_waitcnt lgkmcnt(0)" ::: "memory");
      __builtin_amdgcn_sched_barrier(0);
      __builtin_amdgcn_s_setprio(1);
#pragma unroll
      for (int j = 0; j < 4; ++j)
#pragma unroll
        for (int n = 0; n < 4; ++n)
          acc[p * 4 + j][n] = __builtin_amdgcn_mfma_f32_16x16x32_bf16(
              av[j], bv[n], acc[p * 4 + j][n], 0, 0, 0);
      __builtin_amdgcn_s_setprio(0);
      if (p == 1) {
        if (pre) { asm volatile("s_waitcnt vmcnt(4)" ::: "memory"); }
        else     { asm volatile("s_waitcnt vmcnt(0)" ::: "memory"); }
      }
      __builtin_amdgcn_sched_barrier(0);
      __builtin_amdgcn_s_barrier();
    }
  }

  // epilogue: C/D layout col=lane&15, row=(lane>>4)*4+reg [m89-verified]
  const int crow0 = brow + wrm * 128;
  const int ccol0 = bcol + wcn * 64;
  const int orow  = (lane >> 4) * 4;
  const int ocol  = lane & 15;
#pragma unroll
  for (int m = 0; m < 8; ++m) {
#pragma unroll
    for (int n = 0; n < 4; ++n) {
      const int col = ccol0 + n * 16 + ocol;
#pragma unroll
      for (int j = 0; j < 4; ++j) {
        const int row = crow0 + m * 16 + orow + j;
        const float v = acc[m][n][j];
        if (EPI == 0) {
          unsafeAtomicAdd(&((float*)Cout)[(long)bz * sC + (long)row * ldc + col], v);
        } else {
          ((u16*)Cout)[(long)bz * sC + (long)row * ldc + col] = f2bf(v);
        }
      }
    }
  }
}

// ---------- fp32 -> [hi|lo] bf16 pack (rows x 1024 -> rows x 2048) ----------
__global__ __launch_bounds__(256)
void split_pack(const float* __restrict__ X, u16* __restrict__ P,
                u16* __restrict__ FQ, long n4)
{
  long i = (long)blockIdx.x * 256 + threadIdx.x;
  const long stride = (long)gridDim.x * 256;
  for (; i < n4; i += stride) {
    float4 x = ((const float4*)X)[i];
    long e = i * 4;
    long row = e >> 10;
    int col = (int)(e & 1023);
    float xs[4] = {x.x, x.y, x.z, x.w};
    u16 h[4], l[4];
#pragma unroll
    for (int j = 0; j < 4; ++j) {
      h[j] = f2bf(xs[j]);
      l[j] = f2bf(xs[j] - bf2f(h[j]));
    }
    us4 hv = {h[0], h[1], h[2], h[3]};
    us4 lv = {l[0], l[1], l[2], l[3]};
    *(us4*)(P + row * 2048 + col) = hv;
    *(us4*)(P + row * 2048 + 1024 + col) = lv;
    if (FQ) *(us4*)(FQ + row * 2048 + 1024 + col) = hv;
  }
}

// ---------- accumulated partials + b1 -> hi/lo pack into qr ----------
__global__ __launch_bounds__(256)
void repack_qr(const float* __restrict__ P, const float* __restrict__ b1,
               u16* __restrict__ qr, long n4)
{
  long i = (long)blockIdx.x * 256 + threadIdx.x;
  const long stride = (long)gridDim.x * 256;
  for (; i < n4; i += stride) {
    float4 a = ((const float4*)P)[i];
    long e = i * 4;
    long row = e >> 10;
    int col = (int)(e & 1023);
    float xs[4];
    xs[0] = a.x + b1[col];
    xs[1] = a.y + b1[col + 1];
    xs[2] = a.z + b1[col + 2];
    xs[3] = a.w + b1[col + 3];
    u16 h[4], l[4];
#pragma unroll
    for (int j = 0; j < 4; ++j) {
      h[j] = f2bf(xs[j]);
      l[j] = f2bf(xs[j] - bf2f(h[j]));
    }
    us4 hv = {h[0], h[1], h[2], h[3]};
    us4 lv = {l[0], l[1], l[2], l[3]};
    *(us4*)(qr + row * 2048 + col) = hv;
    *(us4*)(qr + row * 2048 + 1024 + col) = lv;
  }
}

// ---------- accumulated partials + b2, tanh -> out (in place: P == out) ----
__global__ __launch_bounds__(256)
void final_tanh(const float* __restrict__ P, const float* __restrict__ b2,
                float* __restrict__ out, long n4)
{
  long i = (long)blockIdx.x * 256 + threadIdx.x;
  const long stride = (long)gridDim.x * 256;
  for (; i < n4; i += stride) {
    float4 a = ((const float4*)P)[i];
    long e = i * 4;
    int col = (int)(e & 1023);
    float4 o;
    o.x = tanhf(a.x + b2[col]);
    o.y = tanhf(a.y + b2[col + 1]);
    o.z = tanhf(a.z + b2[col + 2]);
    o.w = tanhf(a.w + b2[col + 3]);
    ((float4*)out)[i] = o;
  }
}

// ---------- values: [hi|lo] pack (row-major) + bf16 transpose ----------
__global__ __launch_bounds__(256)
void conv_values(const float* __restrict__ V, u16* __restrict__ Vp,
                 u16* __restrict__ VT)
{
  __shared__ u16 tile[64][68];
  const int b  = blockIdx.z;
  const int d0 = blockIdx.x * 64;
  const int k0 = blockIdx.y * 64;
  const int t  = threadIdx.x;
  const int tr = t >> 4;
  const int tc = (t & 15) * 4;
  const float* Vb = V + (long)b * (1024L * 1024);
  u16* Vpb = Vp + (long)b * (1024L * 2048);
  u16* VTb = VT + (long)b * (1024L * 1024);

#pragma unroll
  for (int i = 0; i < 4; ++i) {
    int k = tr + i * 16;
    float4 x = *(const float4*)(Vb + (long)(k0 + k) * 1024 + d0 + tc);
    float xs[4] = {x.x, x.y, x.z, x.w};
    u16 h[4], l[4];
#pragma unroll
    for (int j = 0; j < 4; ++j) {
      h[j] = f2bf(xs[j]);
      l[j] = f2bf(xs[j] - bf2f(h[j]));
      tile[k][tc + j] = h[j];
    }
    us4 hv = {h[0], h[1], h[2], h[3]};
    us4 lv = {l[0], l[1], l[2], l[3]};
    *(us4*)(Vpb + (long)(k0 + k) * 2048 + d0 + tc) = hv;
    *(us4*)(Vpb + (long)(k0 + k) * 2048 + 1024 + d0 + tc) = lv;
  }
  __syncthreads();
#pragma unroll
  for (int i = 0; i < 4; ++i) {
    int dd = tr + i * 16;
    int k = tc;
    us4 o = {tile[k][dd], tile[k + 1][dd], tile[k + 2][dd], tile[k + 3][dd]};
    *(us4*)(VTb + (long)(d0 + dd) * 1024 + k0 + k) = o;
  }
}

// ---------- plain fp32 -> bf16 cast ----------
__global__ __launch_bounds__(256)
void conv_cast(const float* __restrict__ X, u16* __restrict__ Y, long n4)
{
  long i = (long)blockIdx.x * 256 + threadIdx.x;
  const long stride = (long)gridDim.x * 256;
  for (; i < n4; i += stride) {
    float4 x = ((const float4*)X)[i];
    us4 o = {f2bf(x.x), f2bf(x.y), f2bf(x.z), f2bf(x.w)};
    *(us4*)(Y + i * 4) = o;
  }
}

// ---------- row softmax: fp32 scores[8192][1024] -> bf16 attn ----------
__global__ __launch_bounds__(256)
void softmax_rows(const float* __restrict__ S, u16* __restrict__ A)
{
  const long row = blockIdx.x;
  const float* src = S + row * 1024;
  const int t = threadIdx.x;
  const int lane = t & 63, wid = t >> 6;
  float4 v = ((const float4*)src)[t];
  float m = fmaxf(fmaxf(v.x, v.y), fmaxf(v.z, v.w));
#pragma unroll
  for (int off = 32; off >= 1; off >>= 1)
    m = fmaxf(m, __shfl_xor(m, off));
  __shared__ float redm[4];
  if (lane == 0) redm[wid] = m;
  __syncthreads();
  m = fmaxf(fmaxf(redm[0], redm[1]), fmaxf(redm[2], redm[3]));
  float e0 = __expf(v.x - m), e1 = __expf(v.y - m);
  float e2 = __expf(v.z - m), e3 = __expf(v.w - m);
  float s = e0 + e1 + e2 + e3;
#pragma unroll
  for (int off = 32; off >= 1; off >>= 1)
    s += __shfl_xor(s, off);
  __shared__ float reds[4];
  if (lane == 0) reds[wid] = s;
  __syncthreads();
  s = reds[0] + reds[1] + reds[2] + reds[3];
  float inv = 1.0f / s;
  us4 o = {f2bf(e0 * inv), f2bf(e1 * inv), f2bf(e2 * inv), f2bf(e3 * inv)};
  ((us4*)(A + row * 1024))[t] = o;
}

extern "C" void kernel_launch(void* const* d_in, const int* in_sizes, int n_in,
                              void* d_out, int out_size, void* d_ws, size_t ws_size,
                              hipStream_t stream)
{
  const float* query  = (const float*)d_in[0];  // [8,1024,1024]
  const float* values = (const float*)d_in[1];  // [8,1024,1024]
  const float* W1     = (const float*)d_in[2];  // [1024,1024]
  const float* b1     = (const float*)d_in[3];  // [1024]
  const float* W2     = (const float*)d_in[4];  // [1024,2048]
  const float* b2     = (const float*)d_in[5];  // [1024]
  float* out = (float*)d_out;                   // [8,1024,1024]

  char* ws = (char*)d_ws;
  const long MB = 1024L * 1024;
  // layout (152 MB, lifetime-aliased; K-split partials use d_out + Aq region):
  u16*   W1p    = (u16*)(ws);              //   4 MB  W1 [hi|lo]
  u16*   W2b    = (u16*)(ws + 4 * MB);     //   4 MB  W2 bf16
  u16*   Aq     = (u16*)(ws + 8 * MB);     //  32 MB  query [hi|lo] (dead after G1)
  float* Psc    = (float*)(ws + 8 * MB);   //  32 MB  score partials, aliases Aq
  u16*   qr     = (u16*)(ws + 40 * MB);    //  32 MB  q_resize [hi|lo] (dead after G2)
  u16*   attn   = (u16*)(ws + 40 * MB);    //  16 MB  aliases qr
  u16*   Vp     = (u16*)(ws + 72 * MB);    //  32 MB  values [hi|lo]
  u16*   VT     = (u16*)(ws + 104 * MB);   //  16 MB  values^T bf16
  u16*   feed   = (u16*)(ws + 120 * MB);   //  32 MB  [attended | query] bf16
  float* Pout   = out;                     //  32 MB  G1/G4 partials in d_out

  const long N8M = 8388608;  // 8192*1024

  // conversions
  split_pack<<<dim3(2048), dim3(256), 0, stream>>>(query, Aq, feed, N8M / 4);
  split_pack<<<dim3(1024), dim3(256), 0, stream>>>(W1, W1p, (u16*)nullptr, (1024L * 1024) / 4);
  conv_values<<<dim3(16, 16, 8), dim3(256), 0, stream>>>(values, Vp, VT);
  conv_cast<<<dim3(1024), dim3(256), 0, stream>>>(W2, W2b, (1024L * 2048) / 4);

  // GEMM1: query @ W1^T partial-accumulate into Pout (hi/lo virt-K=3072,
  // ksplit 2; grid 2*1*32*4 = 256)
  hipMemsetAsync(Pout, 0, N8M * 4, stream);
  gemm256<3, 0><<<dim3(256), dim3(512), 0, stream>>>(
      Aq, W1p, Pout, 1024, 2048, 2048, 1024, 0L, 0L, 0L, 1, 32, 4, 48);
  // sum + b1 -> hi/lo qr
  repack_qr<<<dim3(2048), dim3(256), 0, stream>>>(Pout, b1, qr, N8M / 4);

  // GEMM2: qr @ values^T partial-accumulate into Psc (Aq now dead)
  // (hi/lo, batched, ksplit 2; grid 2*8*4*4 = 256)
  hipMemsetAsync(Psc, 0, N8M * 4, stream);
  gemm256<3, 0><<<dim3(256), dim3(512), 0, stream>>>(
      qr, Vp, Psc, 1024, 2048, 2048, 1024, 1024L * 2048, 1024L * 2048,
      1024L * 1024, 8, 4, 4, 48);
  // softmax over keys -> bf16 attn
  softmax_rows<<<dim3(8192), dim3(256), 0, stream>>>(Psc, attn);

  // GEMM3: attended = attn @ values -> feed[:,0:1024] bf16 (no split; 128 blocks)
  gemm256<1, 2><<<dim3(128), dim3(512), 0, stream>>>(
      attn, VT, feed, 1024, 1024, 1024, 2048, 1024L * 1024, 1024L * 1024,
      1024L * 2048, 8, 4, 4, 32);

  // GEMM4: feed @ W2^T partial-accumulate into Pout (K=2048, ksplit 2; 256)
  hipMemsetAsync(Pout, 0, N8M * 4, stream);
  gemm256<1, 0><<<dim3(256), dim3(512), 0, stream>>>(
      feed, W2b, Pout, 2048, 2048, 2048, 1024, 0L, 0L, 0L, 1, 32, 4, 32);
  // + b2, tanh, in place
  final_tanh<<<dim3(2048), dim3(256), 0, stream>>>(Pout, b2, out, N8M / 4);
}